// Round 14
// baseline (29.199 us; speedup 1.0000x reference)
//
#include <hip/hip_runtime.h>
#include <hip/hip_bf16.h>

// Problem constants (match reference)
#define BB 16384
#define DD 512
#define NCLS 90
#define KC 32
#define BUCKET 512           // max samples per class (mean 182, +24 sigma headroom)
#define MAGIC 0x7f3a9c51u    // per-class "binning done" flag value

typedef __attribute__((ext_vector_type(8))) short short8;   // 8 bf16 (4 VGPRs)
typedef __attribute__((ext_vector_type(4))) float fx4;      // MFMA accumulator

// pack 8 f32 -> 8 bf16 via v_cvt_pk_bf16_f32 (RNE), optional scale
static __device__ __forceinline__ short8 pack8s(float sc, float4 a, float4 b) {
    union { __hip_bfloat162 h[4]; short8 s; } u;
    u.h[0] = __float22bfloat162_rn(make_float2(a.x * sc, a.y * sc));
    u.h[1] = __float22bfloat162_rn(make_float2(a.z * sc, a.w * sc));
    u.h[2] = __float22bfloat162_rn(make_float2(b.x * sc, b.y * sc));
    u.h[3] = __float22bfloat162_rn(make_float2(b.z * sc, b.w * sc));
    return u.s;
}
static __device__ __forceinline__ short8 pack8(float4 a, float4 b) {
    union { __hip_bfloat162 h[4]; short8 s; } u;
    u.h[0] = __float22bfloat162_rn(make_float2(a.x, a.y));
    u.h[1] = __float22bfloat162_rn(make_float2(a.z, a.w));
    u.h[2] = __float22bfloat162_rn(make_float2(b.x, b.y));
    u.h[3] = __float22bfloat162_rn(make_float2(b.z, b.w));
    return u.s;
}

// ---- K1: fused binning (p==0) + in-block center norm + flag + chunk loop ----
// grid = 720, 256 thr. Blocks 0..89 are (c=b, p=0): bin class c first (binners
// co-resident from dispatch -> no deadlock), release flag[c]. All blocks then
// normalize class c's centers f32->bf16 directly into c_lds (overlaps the
// workers' flag wait). Chunk loop = R13's batch-issued gather + MFMA + softmax.
__global__ __launch_bounds__(256, 2)
void k_all(const float* __restrict__ x,
           const float* __restrict__ centers,
           const int* __restrict__ labels,
           int* __restrict__ idx,
           int* __restrict__ cnt,
           unsigned int* __restrict__ flag,
           float* __restrict__ partials) {
    __shared__ __align__(16) char u_lds[64 * 1024];  // lab[16K int] | c_lds+x_lds
    __shared__ float S_lds[32][33];
    __shared__ float xinv[32];
    __shared__ float red4[4];
    __shared__ int wcnt[4];

    int*   lab   = (int*)u_lds;                      // binning phase only
    short* c_lds = (short*)u_lds;                    // 32 KiB bf16, XOR-swizzled
    short* x_lds = (short*)(u_lds + 32768);          // 32 KiB bf16, XOR-swizzled

    int b = blockIdx.x;
    int c, p;
    if (b < NCLS) { c = b; p = 0; }
    else { c = (b - NCLS) / 7; p = 1 + (b - NCLS) % 7; }
    int t = threadIdx.x, w = t >> 6, lane = t & 63;

    if (p == 0) {
        // ---- bin class c: labels -> LDS, count, ballot-compaction emit ----
        for (int j = t; j < BB / 4; j += 256)        // coalesced int4 load
            ((int4*)lab)[j] = ((const int4*)labels)[j];
        __syncthreads();
        int seg4 = w * (BB / 4 / 4);                 // 1024 int4 per wave
        int cw = 0;
#pragma unroll
        for (int jj = 0; jj < 16; jj++) {
            int4 v = ((int4*)lab)[seg4 + jj * 64 + lane];
            cw += (v.x == c) + (v.y == c) + (v.z == c) + (v.w == c);
        }
#pragma unroll
        for (int m = 1; m < 64; m <<= 1) cw += __shfl_xor(cw, m, 64);
        if (lane == 0) wcnt[w] = cw;
        __syncthreads();
        int n0 = wcnt[0] + wcnt[1] + wcnt[2] + wcnt[3];
        int pos = c * BUCKET;
        for (int ww = 0; ww < w; ww++) pos += wcnt[ww];
#pragma unroll
        for (int jj = 0; jj < 16; jj++) {
            int4 v = ((int4*)lab)[seg4 + jj * 64 + lane];
            int gbase = (seg4 + jj * 64 + lane) * 4;
            { bool m = (v.x == c); unsigned long long k = __ballot(m);
              if (m) idx[pos + __popcll(k & ((1ull << lane) - 1ull))] = gbase;     pos += __popcll(k); }
            { bool m = (v.y == c); unsigned long long k = __ballot(m);
              if (m) idx[pos + __popcll(k & ((1ull << lane) - 1ull))] = gbase + 1; pos += __popcll(k); }
            { bool m = (v.z == c); unsigned long long k = __ballot(m);
              if (m) idx[pos + __popcll(k & ((1ull << lane) - 1ull))] = gbase + 2; pos += __popcll(k); }
            { bool m = (v.w == c); unsigned long long k = __ballot(m);
              if (m) idx[pos + __popcll(k & ((1ull << lane) - 1ull))] = gbase + 3; pos += __popcll(k); }
        }
        // zero-fill bucket tail -> unclamped gathers are safe
        for (int j = n0 + t; j < BUCKET; j += 256) idx[c * BUCKET + j] = 0;
        __syncthreads();                             // all lab reads + stores done
        if (t == 0) {
            cnt[c] = n0;
            __hip_atomic_store(&flag[c], MAGIC, __ATOMIC_RELEASE, __HIP_MEMORY_SCOPE_AGENT);
        }
    }

    // ---- normalize class c's 32 center rows into c_lds (all blocks) ----
    {
        int row8 = t >> 3, l8 = t & 7;               // 8 threads per center row
        const float4* csrc = (const float4*)(centers + ((size_t)c * KC + row8) * DD);
        float s = 0.f;
#pragma unroll
        for (int jj = 0; jj < 8; jj++) {
            float4 a = csrc[(l8 + 8 * jj) * 2], b4 = csrc[(l8 + 8 * jj) * 2 + 1];
            s += a.x * a.x + a.y * a.y + a.z * a.z + a.w * a.w
               + b4.x * b4.x + b4.y * b4.y + b4.z * b4.z + b4.w * b4.w;
        }
#pragma unroll
        for (int m = 1; m < 8; m <<= 1) s += __shfl_xor(s, m, 64);
        float sc = rsqrtf(s + 1e-12f);
#pragma unroll
        for (int jj = 0; jj < 8; jj++) {             // second pass: L1 re-hit
            int c16 = l8 + 8 * jj;
            float4 a = csrc[c16 * 2], b4 = csrc[c16 * 2 + 1];
            *(short8*)&c_lds[row8 * DD + ((c16 ^ (row8 & 7)) << 3)] = pack8s(sc, a, b4);
        }
    }

    // ---- workers wait for binning (overlapped with the norm work above) ----
    if (p != 0 && t == 0) {
        while (__hip_atomic_load(&flag[c], __ATOMIC_ACQUIRE, __HIP_MEMORY_SCOPE_AGENT) != MAGIC)
            __builtin_amdgcn_s_sleep(2);
    }
    __syncthreads();                                 // c_lds ready + flag acquired

    int n = cnt[c];
    int nch = (n + 31) >> 5;
    float loss_acc = 0.f;

    if (p < nch) {
        int base = c * BUCKET;
        int mrow = ((w & 1) << 4) + (lane & 15);
        int nrow = ((w >> 1) << 4) + (lane & 15);
        int row8 = t >> 3, l8 = t & 7;               // 8 threads per sample row

        for (int ch = p; ch < nch; ch += 8) {
            int off = ch << 5;
            int rem = n - off;                       // > 0

            // ---- gather raw f32 x row: ISSUE ALL 16 LOADS FIRST (R13/T14) ----
            {
                int g = idx[base + off + row8];      // tail rows -> idx 0 (safe)
                const float4* src = (const float4*)(x + (size_t)g * DD);
                float4 va[8], vb[8];
#pragma unroll
                for (int jj = 0; jj < 8; jj++) {     // 16 independent 16B loads
                    va[jj] = src[2 * l8 + 16 * jj];
                    vb[jj] = src[2 * l8 + 16 * jj + 1];
                }
                float nrm = 0.f;
#pragma unroll
                for (int jj = 0; jj < 8; jj++) {     // use phase: norm + cvt + LDS
                    int cc = l8 + 8 * jj;            // 16B bf16 chunk 0..63
                    float4 a = va[jj], b4 = vb[jj];
                    nrm += a.x * a.x + a.y * a.y + a.z * a.z + a.w * a.w
                         + b4.x * b4.x + b4.y * b4.y + b4.z * b4.z + b4.w * b4.w;
                    *(short8*)&x_lds[row8 * DD + ((cc ^ (row8 & 7)) << 3)] = pack8(a, b4);
                }
#pragma unroll
                for (int m = 1; m < 8; m <<= 1) nrm += __shfl_xor(nrm, m, 64);
                if (l8 == 0) xinv[row8] = rsqrtf(nrm + 1e-12f);
            }
            __syncthreads();

            // ---- MFMA: S[32 samples][32 k] in 4 wave-quadrants ----
            fx4 acc = {0.f, 0.f, 0.f, 0.f};
#pragma unroll
            for (int ks = 0; ks < 16; ks++) {
                int c16a = ks * 4 + (lane >> 4);
                short8 av = *(const short8*)&x_lds[mrow * DD + ((c16a ^ (mrow & 7)) << 3)];
                short8 bv = *(const short8*)&c_lds[nrow * DD + ((c16a ^ (nrow & 7)) << 3)];
                acc = __builtin_amdgcn_mfma_f32_16x16x32_bf16(av, bv, acc, 0, 0, 0);
            }
#pragma unroll
            for (int j = 0; j < 4; j++) {
                int r = ((w & 1) << 4) + ((lane >> 4) << 2) + j;   // C/D row
                int col = ((w >> 1) << 4) + (lane & 15);           // C/D col
                S_lds[r][col] = acc[j];
            }
            __syncthreads();

            // ---- softmax over K=32 + per-sample loss; 8 threads per row ----
            {
                float xv = xinv[row8];
                int q4 = l8 << 2;
                float s0 = S_lds[row8][q4 + 0] * xv;
                float s1 = S_lds[row8][q4 + 1] * xv;
                float s2 = S_lds[row8][q4 + 2] * xv;
                float s3 = S_lds[row8][q4 + 3] * xv;
                float mx = fmaxf(fmaxf(s0, s1), fmaxf(s2, s3));
#pragma unroll
                for (int m = 1; m < 8; m <<= 1) mx = fmaxf(mx, __shfl_xor(mx, m, 64));
                float e0 = expf(s0 - mx), e1 = expf(s1 - mx);
                float e2 = expf(s2 - mx), e3 = expf(s3 - mx);
                float Z = e0 + e1 + e2 + e3;
                float num = e0 * (1.f - s0) + e1 * (1.f - s1)
                          + e2 * (1.f - s2) + e3 * (1.f - s3);
#pragma unroll
                for (int m = 1; m < 8; m <<= 1) {
                    Z += __shfl_xor(Z, m, 64);
                    num += __shfl_xor(num, m, 64);
                }
                if (l8 == 0 && row8 < rem) loss_acc += num / Z;
            }
            __syncthreads();   // protect x_lds/S_lds before next chunk
        }
    }

    // ---- slim per-wave tail reduce: 1 barrier instead of 8 ----
#pragma unroll
    for (int m = 1; m < 64; m <<= 1) loss_acc += __shfl_xor(loss_acc, m, 64);
    if (lane == 0) red4[w] = loss_acc;
    __syncthreads();
    if (t == 0) partials[b] = red4[0] + red4[1] + red4[2] + red4[3];
}

// ---- K2: deterministic final mean over 720 block partials -------------------
__global__ void k_final(const float* __restrict__ partials, float* __restrict__ out) {
    __shared__ float red[256];
    int t = threadIdx.x;
    float s = 0.f;
    for (int i = t; i < NCLS * 8; i += 256) s += partials[i];
    red[t] = s;
    __syncthreads();
    for (int h = 128; h > 0; h >>= 1) {
        if (t < h) red[t] += red[t + h];
        __syncthreads();
    }
    if (t == 0) out[0] = red[0] * (1.0f / (float)BB);
}

extern "C" void kernel_launch(void* const* d_in, const int* in_sizes, int n_in,
                              void* d_out, int out_size, void* d_ws, size_t ws_size,
                              hipStream_t stream) {
    const float* x       = (const float*)d_in[0];
    const int*   labels  = (const int*)d_in[1];
    const float* centers = (const float*)d_in[2];
    float* out = (float*)d_out;

    char* ws = (char*)d_ws;
    int*          idx      = (int*)(ws + 0);        // 90*512 ints = 184,320 B
    int*          cnt      = (int*)(ws + 184320);   // 90 ints
    unsigned int* flag     = (unsigned int*)(ws + 184832); // 90 words
    float*        partials = (float*)(ws + 196608); // 720 floats (all written)

    k_all<<<NCLS * 8, 256, 0, stream>>>(x, centers, labels, idx, cnt, flag, partials);
    k_final<<<1, 256, 0, stream>>>(partials, out);
}